// Round 11
// baseline (949.512 us; speedup 1.0000x reference)
//
#include <hip/hip_runtime.h>

#define PNPB 32   // nodes per proj block
#define TILE 32   // edges per wave-tile in alpha

// ---------------------------------------------------------------------------
// Projection kernel: q/k/v_inv (4h x 60), q/k_ev (3h x 80).
// ---------------------------------------------------------------------------
__global__ __launch_bounds__(512) void proj_kernel(
    const float* __restrict__ x,
    const float* __restrict__ Wq, const float* __restrict__ Wk,
    const float* __restrict__ Wv,
    const float* __restrict__ Wqe, const float* __restrict__ Wke,
    float* __restrict__ q_inv, float* __restrict__ k_inv,
    float* __restrict__ v_inv,
    float* __restrict__ q_ev, float* __restrict__ k_ev, int N)
{
    __shared__ float xs[PNPB * 240];
    const int base_node = blockIdx.x * PNPB;
    for (int idx = threadIdx.x; idx < PNPB * 240; idx += 512) {
        int g = base_node * 240 + idx;
        xs[idx] = (g < N * 240) ? x[g] : 0.f;
    }
    __syncthreads();

    const int slot = threadIdx.x & 63;
    const int wg   = threadIdx.x >> 6;       // 0..7
    if (slot >= 60) return;

    const int hi  = slot / 15;
    const int jdi = slot * 4 - hi * 60;
    const int he  = slot / 20;
    const int jde = slot * 4 - he * 80;
    const int nl0 = wg * 4;

    float4 aq[4], ak[4], av[4], aqe[4], ake[4];
    #pragma unroll
    for (int n = 0; n < 4; ++n) {
        aq[n] = make_float4(0.f,0.f,0.f,0.f); ak[n] = aq[n]; av[n] = aq[n];
        aqe[n] = aq[n]; ake[n] = aq[n];
    }
    {
        const float* wq = Wq + hi * 3600 + jdi;
        const float* wk = Wk + hi * 3600 + jdi;
        const float* wv = Wv + hi * 3600 + jdi;
        const float* xb = &xs[nl0 * 240 + hi * 60];
        #pragma unroll 2
        for (int i = 0; i < 60; ++i) {
            float xv0 = xb[i], xv1 = xb[240 + i], xv2 = xb[480 + i], xv3 = xb[720 + i];
            float4 w;
            w = *(const float4*)&wq[i * 60];
            aq[0].x += xv0*w.x; aq[0].y += xv0*w.y; aq[0].z += xv0*w.z; aq[0].w += xv0*w.w;
            aq[1].x += xv1*w.x; aq[1].y += xv1*w.y; aq[1].z += xv1*w.z; aq[1].w += xv1*w.w;
            aq[2].x += xv2*w.x; aq[2].y += xv2*w.y; aq[2].z += xv2*w.z; aq[2].w += xv2*w.w;
            aq[3].x += xv3*w.x; aq[3].y += xv3*w.y; aq[3].z += xv3*w.z; aq[3].w += xv3*w.w;
            w = *(const float4*)&wk[i * 60];
            ak[0].x += xv0*w.x; ak[0].y += xv0*w.y; ak[0].z += xv0*w.z; ak[0].w += xv0*w.w;
            ak[1].x += xv1*w.x; ak[1].y += xv1*w.y; ak[1].z += xv1*w.z; ak[1].w += xv1*w.w;
            ak[2].x += xv2*w.x; ak[2].y += xv2*w.y; ak[2].z += xv2*w.z; ak[2].w += xv2*w.w;
            ak[3].x += xv3*w.x; ak[3].y += xv3*w.y; ak[3].z += xv3*w.z; ak[3].w += xv3*w.w;
            w = *(const float4*)&wv[i * 60];
            av[0].x += xv0*w.x; av[0].y += xv0*w.y; av[0].z += xv0*w.z; av[0].w += xv0*w.w;
            av[1].x += xv1*w.x; av[1].y += xv1*w.y; av[1].z += xv1*w.z; av[1].w += xv1*w.w;
            av[2].x += xv2*w.x; av[2].y += xv2*w.y; av[2].z += xv2*w.z; av[2].w += xv2*w.w;
            av[3].x += xv3*w.x; av[3].y += xv3*w.y; av[3].z += xv3*w.z; av[3].w += xv3*w.w;
        }
    }
    {
        const float* wq = Wqe + he * 6400 + jde;
        const float* wk = Wke + he * 6400 + jde;
        const float* xb = &xs[nl0 * 240 + he * 80];
        #pragma unroll 2
        for (int i = 0; i < 80; ++i) {
            float xv0 = xb[i], xv1 = xb[240 + i], xv2 = xb[480 + i], xv3 = xb[720 + i];
            float4 w;
            w = *(const float4*)&wq[i * 80];
            aqe[0].x += xv0*w.x; aqe[0].y += xv0*w.y; aqe[0].z += xv0*w.z; aqe[0].w += xv0*w.w;
            aqe[1].x += xv1*w.x; aqe[1].y += xv1*w.y; aqe[1].z += xv1*w.z; aqe[1].w += xv1*w.w;
            aqe[2].x += xv2*w.x; aqe[2].y += xv2*w.y; aqe[2].z += xv2*w.z; aqe[2].w += xv2*w.w;
            aqe[3].x += xv3*w.x; aqe[3].y += xv3*w.y; aqe[3].z += xv3*w.z; aqe[3].w += xv3*w.w;
            w = *(const float4*)&wk[i * 80];
            ake[0].x += xv0*w.x; ake[0].y += xv0*w.y; ake[0].z += xv0*w.z; ake[0].w += xv0*w.w;
            ake[1].x += xv1*w.x; ake[1].y += xv1*w.y; ake[1].z += xv1*w.z; ake[1].w += xv1*w.w;
            ake[2].x += xv2*w.x; ake[2].y += xv2*w.y; ake[2].z += xv2*w.z; ake[2].w += xv2*w.w;
            ake[3].x += xv3*w.x; ake[3].y += xv3*w.y; ake[3].z += xv3*w.z; ake[3].w += xv3*w.w;
        }
    }
    #pragma unroll
    for (int n = 0; n < 4; ++n) {
        const int node = base_node + nl0 + n;
        if (node >= N) break;
        const int ob = node * 240 + slot * 4;
        *(float4*)&q_inv[ob] = aq[n];
        *(float4*)&k_inv[ob] = ak[n];
        *(float4*)&v_inv[ob] = av[n];
        *(float4*)&q_ev[ob]  = aqe[n];
        *(float4*)&k_ev[ob]  = ake[n];
    }
}

// ---------------------------------------------------------------------------
// CSR build
// ---------------------------------------------------------------------------
__global__ __launch_bounds__(256) void hist_kernel(
    const int* __restrict__ rcv, int* __restrict__ counts, int E)
{
    int e = blockIdx.x * 256 + threadIdx.x;
    if (e < E) atomicAdd(&counts[rcv[e]], 1);
}

__global__ __launch_bounds__(1024) void scan_kernel(
    const int* __restrict__ counts, int* __restrict__ rowstart,
    int* __restrict__ cursor, int N)
{
    __shared__ int wsum[16];
    __shared__ int carry_s;
    if (threadIdx.x == 0) carry_s = 0;
    __syncthreads();
    const int lane = threadIdx.x & 63;
    const int w    = threadIdx.x >> 6;
    for (int base = 0; base < N; base += 1024) {
        const int i = base + threadIdx.x;
        int v = (i < N) ? counts[i] : 0;
        int x = v;
        #pragma unroll
        for (int off = 1; off < 64; off <<= 1) {
            int t = __shfl_up(x, off);
            if (lane >= off) x += t;
        }
        if (lane == 63) wsum[w] = x;
        __syncthreads();
        if (w == 0) {
            int s = (lane < 16) ? wsum[lane] : 0;
            #pragma unroll
            for (int off = 1; off < 16; off <<= 1) {
                int t = __shfl_up(s, off);
                if (lane >= off) s += t;
            }
            if (lane < 16) wsum[lane] = s;
        }
        __syncthreads();
        const int woff = (w == 0) ? 0 : wsum[w - 1];
        const int ex = carry_s + woff + x - v;
        if (i < N) { rowstart[i] = ex; cursor[i] = ex; }
        __syncthreads();
        if (threadIdx.x == 1023) carry_s += wsum[15];
    }
    __syncthreads();
    if (threadIdx.x == 0) rowstart[N] = carry_s;
}

__global__ __launch_bounds__(256) void scatter_kernel(
    const int* __restrict__ rcv, int* __restrict__ cursor,
    int* __restrict__ csr, int E)
{
    int e = blockIdx.x * 256 + threadIdx.x;
    if (e < E) {
        int pos = atomicAdd(&cursor[rcv[e]], 1);
        csr[pos] = e;
    }
}

// ---------------------------------------------------------------------------
// Per-edge SO3 invariants -> inv3[e][4]
// ---------------------------------------------------------------------------
__global__ __launch_bounds__(256) void inv3_kernel(
    const float* __restrict__ ev_f, const int* __restrict__ snd,
    const int* __restrict__ rcv, float* __restrict__ inv3, int E)
{
    int e = blockIdx.x * 256 + threadIdx.x;
    if (e >= E) return;
    const float* es = ev_f + (size_t)snd[e] * 15;
    const float* er = ev_f + (size_t)rcv[e] * 15;
    float i0 = 0.f, i1 = 0.f, i2 = 0.f;
    #pragma unroll
    for (int q = 0; q < 3; ++q)  { float d = es[q] - er[q]; i0 = fmaf(d, d, i0); }
    #pragma unroll
    for (int q = 3; q < 8; ++q)  { float d = es[q] - er[q]; i1 = fmaf(d, d, i1); }
    #pragma unroll
    for (int q = 8; q < 15; ++q) { float d = es[q] - er[q]; i2 = fmaf(d, d, i2); }
    *(float4*)(inv3 + (size_t)e * 4) = make_float4(i0, i1, i2, 0.f);
}

// ---------------------------------------------------------------------------
// Fused alpha: blockIdx.y = 0 -> invariant heads, 1 -> equivariant heads.
// Wave owns a TILE(32)-edge CSR tile staged in LDS; per-lane W slice
// (35 x float4); f broadcast via ds_read_b128. 10000 waves total -> ~16
// resident waves/CU (VGPR<=128 via launch_bounds(256,4)) vs R10's 2.4/SIMD.
// part 0: lane=16h+m (m<15), j0=60h+4m, 16-wide shfl_xor reduce.
// part 1: lane<60, h=l/20, m=l%20, j0=80h+4m, 20-lane predicated reduce.
// ---------------------------------------------------------------------------
__global__ __launch_bounds__(256, 4) void alpha_fused_kernel(
    const float* __restrict__ rbf, const float* __restrict__ inv3,
    const float* __restrict__ cut,
    const float* __restrict__ Wfi, const float* __restrict__ bfi,
    const float* __restrict__ Wfe, const float* __restrict__ bfe,
    const int* __restrict__ snd, const int* __restrict__ rcv,
    const int* __restrict__ csr,
    const float* __restrict__ q_inv, const float* __restrict__ k_inv,
    const float* __restrict__ q_ev,  const float* __restrict__ k_ev,
    float* __restrict__ alpha, int E)
{
    __shared__ float fs[4][TILE * 36];
    __shared__ int   ss[4][TILE], sr[4][TILE];

    const int lane = threadIdx.x & 63;
    const int wid  = threadIdx.x >> 6;
    const int part = blockIdx.y;              // wave-uniform

    int h, m, j0; bool act;
    if (part == 0) {
        h = lane >> 4; m = lane & 15; act = (m < 15);
        j0 = h * 60 + (act ? m * 4 : 0);
    } else {
        act = (lane < 60);
        h = act ? (lane / 20) : 0;
        m = act ? (lane % 20) : 0;
        j0 = 80 * h + 4 * m;
    }

    const float* Wf = part ? Wfe : Wfi;
    const float* bf = part ? bfe : bfi;
    const float* qbase = part ? q_ev : q_inv;
    const float* kbase = part ? k_ev : k_inv;
    const float scale = part ? 0.11180339887498948f : 0.12909944487358056f;

    float4 w[35];
    #pragma unroll
    for (int k = 0; k < 35; ++k)
        w[k] = *(const float4*)(Wf + k * 240 + j0);
    const float4 b4 = *(const float4*)(bf + j0);

    const int tbase = (blockIdx.x * 4 + wid) * TILE;
    if (lane < TILE) {
        int i = tbase + lane;
        if (i >= E) i = E - 1;
        const int e = csr[i];
        float* frow = &fs[wid][lane * 36];
        const float4* rb = (const float4*)(rbf + (size_t)e * 32);
        #pragma unroll
        for (int k4 = 0; k4 < 8; ++k4)
            *(float4*)&frow[k4 * 4] = rb[k4];
        const float4 v3 = *(const float4*)(inv3 + (size_t)e * 4);
        frow[32] = v3.x; frow[33] = v3.y; frow[34] = v3.z;
        frow[35] = cut[e];
        ss[wid][lane] = snd[e];
        sr[wid][lane] = rcv[e];
    }
    __syncthreads();

    #pragma unroll 2
    for (int t = 0; t < TILE; ++t) {
        const int gi = tbase + t;
        if (gi >= E) break;
        const int s = ss[wid][t];
        const int r = sr[wid][t];
        const float* frow = &fs[wid][t * 36];

        float4 fw = b4;
        #pragma unroll
        for (int k4 = 0; k4 < 8; ++k4) {
            const float4 f4 = *(const float4*)&frow[k4 * 4];
            const float4 w0 = w[k4*4+0], w1 = w[k4*4+1], w2 = w[k4*4+2], w3 = w[k4*4+3];
            fw.x = fmaf(f4.x, w0.x, fw.x); fw.y = fmaf(f4.x, w0.y, fw.y);
            fw.z = fmaf(f4.x, w0.z, fw.z); fw.w = fmaf(f4.x, w0.w, fw.w);
            fw.x = fmaf(f4.y, w1.x, fw.x); fw.y = fmaf(f4.y, w1.y, fw.y);
            fw.z = fmaf(f4.y, w1.z, fw.z); fw.w = fmaf(f4.y, w1.w, fw.w);
            fw.x = fmaf(f4.z, w2.x, fw.x); fw.y = fmaf(f4.z, w2.y, fw.y);
            fw.z = fmaf(f4.z, w2.z, fw.z); fw.w = fmaf(f4.z, w2.w, fw.w);
            fw.x = fmaf(f4.w, w3.x, fw.x); fw.y = fmaf(f4.w, w3.y, fw.y);
            fw.z = fmaf(f4.w, w3.z, fw.z); fw.w = fmaf(f4.w, w3.w, fw.w);
        }
        {
            const float fa = frow[32], fb = frow[33], fc = frow[34];
            const float4 wa = w[32], wb = w[33], wc = w[34];
            fw.x = fmaf(fa, wa.x, fw.x); fw.y = fmaf(fa, wa.y, fw.y);
            fw.z = fmaf(fa, wa.z, fw.z); fw.w = fmaf(fa, wa.w, fw.w);
            fw.x = fmaf(fb, wb.x, fw.x); fw.y = fmaf(fb, wb.y, fw.y);
            fw.z = fmaf(fb, wb.z, fw.z); fw.w = fmaf(fb, wb.w, fw.w);
            fw.x = fmaf(fc, wc.x, fw.x); fw.y = fmaf(fc, wc.y, fw.y);
            fw.z = fmaf(fc, wc.z, fw.z); fw.w = fmaf(fc, wc.w, fw.w);
        }
        const float cc = frow[35];

        const float4 q  = *(const float4*)(qbase + (size_t)r * 240 + j0);
        const float4 kk = *(const float4*)(kbase + (size_t)s * 240 + j0);
        float d = act ? (q.x*kk.x*fw.x + q.y*kk.y*fw.y
                       + q.z*kk.z*fw.z + q.w*kk.w*fw.w) : 0.f;

        if (part == 0) {
            #pragma unroll
            for (int off = 1; off < 16; off <<= 1) d += __shfl_xor(d, off, 16);
            if (m == 0)    alpha[(size_t)gi * 8 + h] = d * scale * cc;
            if (lane == 0) alpha[(size_t)gi * 8 + 7] = __int_as_float(s);
        } else {
            float tt;
            tt = __shfl(d, (lane + 10) & 63); if (m < 10) d += tt;
            tt = __shfl(d, (lane + 5) & 63);  if (m < 5)  d += tt;
            const int gb = h * 20;
            const float t1 = __shfl(d, gb + 1);
            const float t2 = __shfl(d, gb + 2);
            const float t3 = __shfl(d, gb + 3);
            const float t4 = __shfl(d, gb + 4);
            if (act && m == 0)
                alpha[(size_t)gi * 8 + 4 + h] = (d + t1 + t2 + t3 + t4) * scale * cc;
        }
    }
}

// ---------------------------------------------------------------------------
// Gather: one block per receiver; alpha indexed by CSR position.
// ---------------------------------------------------------------------------
__global__ __launch_bounds__(256) void gather_kernel(
    const int* __restrict__ rowstart, const int* __restrict__ csr,
    const float* __restrict__ alpha,
    const float* __restrict__ v_inv, const float* __restrict__ sh,
    float* __restrict__ dinv, float* __restrict__ dev)
{
    const int r = blockIdx.x;
    const int c = threadIdx.x;
    const int beg = rowstart[r], end = rowstart[r + 1];

    __shared__ float sal[64][8];
    __shared__ int   sed[64];

    float acc = 0.f;
    for (int chunk = beg; chunk < end; chunk += 64) {
        const int len = min(64, end - chunk);
        __syncthreads();
        if (c < len) {
            const float4* ap = (const float4*)(alpha + (size_t)(chunk + c) * 8);
            const float4 a0 = ap[0], a1 = ap[1];
            *(float4*)&sal[c][0] = a0;
            *(float4*)&sal[c][4] = a1;
            sed[c] = csr[chunk + c];
        }
        __syncthreads();
        if (c < 240) {
            const int h = c / 60;
            #pragma unroll 4
            for (int i = 0; i < len; ++i) {
                const int s = __float_as_int(sal[i][7]);
                acc += sal[i][h] * v_inv[(size_t)s * 240 + c];
            }
        } else if (c < 255) {
            const int i0 = c - 240;
            const int h = (i0 < 3) ? 4 : ((i0 < 8) ? 5 : 6);
            for (int i = 0; i < len; ++i)
                acc += sal[i][h] * sh[(size_t)sed[i] * 15 + i0];
        }
    }
    if (c < 240) dinv[(size_t)r * 240 + c] = acc;
    else if (c < 255) dev[(size_t)r * 15 + (c - 240)] = acc;
}

extern "C" void kernel_launch(void* const* d_in, const int* in_sizes, int n_in,
                              void* d_out, int out_size, void* d_ws, size_t ws_size,
                              hipStream_t stream) {
    const float* inv_f = (const float*)d_in[0];
    const float* ev_f  = (const float*)d_in[1];
    const float* rbf   = (const float*)d_in[2];
    const float* sh    = (const float*)d_in[3];
    const float* cut   = (const float*)d_in[4];
    const float* Wq    = (const float*)d_in[5];
    const float* Wk    = (const float*)d_in[6];
    const float* Wv    = (const float*)d_in[7];
    const float* Wqe   = (const float*)d_in[8];
    const float* Wke   = (const float*)d_in[9];
    const float* Wfi   = (const float*)d_in[10];
    const float* bfi   = (const float*)d_in[11];
    const float* Wfe   = (const float*)d_in[12];
    const float* bfe   = (const float*)d_in[13];
    const int*   snd   = (const int*)d_in[14];
    const int*   rcv   = (const int*)d_in[15];

    const int N = in_sizes[0] / 240;
    const int E = in_sizes[14];

    float* out  = (float*)d_out;
    float* dinv = out;                       // [N,240]
    float* dev  = out + (size_t)N * 240;     // [N,15]

    float* ws = (float*)d_ws;
    const size_t Nf = (size_t)N * 240;
    float* q_inv = ws + 0 * Nf;
    float* k_inv = ws + 1 * Nf;
    float* v_inv = ws + 2 * Nf;
    float* q_ev  = ws + 3 * Nf;
    float* k_ev  = ws + 4 * Nf;
    float* alpha = ws + 5 * Nf;                           // E*8 floats
    float* inv3  = alpha + (size_t)E * 8;                 // E*4 floats
    int*   ibase    = (int*)(inv3 + (size_t)E * 4);
    int*   counts   = ibase;                              // N
    int*   rowstart = ibase + N;                          // N+1
    int*   cursor   = ibase + 2 * N + 1;                  // N
    int*   csr      = ibase + 3 * N + 1;                  // E

    hipMemsetAsync(counts, 0, (size_t)N * sizeof(int), stream);

    const int eb = (E + 255) / 256;
    hist_kernel<<<eb, 256, 0, stream>>>(rcv, counts, E);
    scan_kernel<<<1, 1024, 0, stream>>>(counts, rowstart, cursor, N);
    scatter_kernel<<<eb, 256, 0, stream>>>(rcv, cursor, csr, E);

    proj_kernel<<<(N + PNPB - 1) / PNPB, 512, 0, stream>>>(
        inv_f, Wq, Wk, Wv, Wqe, Wke, q_inv, k_inv, v_inv, q_ev, k_ev, N);

    inv3_kernel<<<eb, 256, 0, stream>>>(ev_f, snd, rcv, inv3, E);

    const int ab = (E + 4 * TILE - 1) / (4 * TILE);   // 4 waves x TILE edges
    alpha_fused_kernel<<<dim3(ab, 2), 256, 0, stream>>>(
        rbf, inv3, cut, Wfi, bfi, Wfe, bfe, snd, rcv, csr,
        q_inv, k_inv, q_ev, k_ev, alpha, E);

    gather_kernel<<<N, 256, 0, stream>>>(
        rowstart, csr, alpha, v_inv, sh, dinv, dev);
}

// Round 12
// 354.054 us; speedup vs baseline: 2.6818x; 2.6818x over previous
//
#include <hip/hip_runtime.h>

#define PNPB 32   // nodes per proj block

// ---------------------------------------------------------------------------
// Projection kernel: q/k/v_inv (4h x 60), q/k_ev (3h x 80).
// ---------------------------------------------------------------------------
__global__ __launch_bounds__(512) void proj_kernel(
    const float* __restrict__ x,
    const float* __restrict__ Wq, const float* __restrict__ Wk,
    const float* __restrict__ Wv,
    const float* __restrict__ Wqe, const float* __restrict__ Wke,
    float* __restrict__ q_inv, float* __restrict__ k_inv,
    float* __restrict__ v_inv,
    float* __restrict__ q_ev, float* __restrict__ k_ev, int N)
{
    __shared__ float xs[PNPB * 240];
    const int base_node = blockIdx.x * PNPB;
    for (int idx = threadIdx.x; idx < PNPB * 240; idx += 512) {
        int g = base_node * 240 + idx;
        xs[idx] = (g < N * 240) ? x[g] : 0.f;
    }
    __syncthreads();

    const int slot = threadIdx.x & 63;
    const int wg   = threadIdx.x >> 6;       // 0..7
    if (slot >= 60) return;

    const int hi  = slot / 15;
    const int jdi = slot * 4 - hi * 60;
    const int he  = slot / 20;
    const int jde = slot * 4 - he * 80;
    const int nl0 = wg * 4;

    float4 aq[4], ak[4], av[4], aqe[4], ake[4];
    #pragma unroll
    for (int n = 0; n < 4; ++n) {
        aq[n] = make_float4(0.f,0.f,0.f,0.f); ak[n] = aq[n]; av[n] = aq[n];
        aqe[n] = aq[n]; ake[n] = aq[n];
    }
    {
        const float* wq = Wq + hi * 3600 + jdi;
        const float* wk = Wk + hi * 3600 + jdi;
        const float* wv = Wv + hi * 3600 + jdi;
        const float* xb = &xs[nl0 * 240 + hi * 60];
        #pragma unroll 2
        for (int i = 0; i < 60; ++i) {
            float xv0 = xb[i], xv1 = xb[240 + i], xv2 = xb[480 + i], xv3 = xb[720 + i];
            float4 w;
            w = *(const float4*)&wq[i * 60];
            aq[0].x += xv0*w.x; aq[0].y += xv0*w.y; aq[0].z += xv0*w.z; aq[0].w += xv0*w.w;
            aq[1].x += xv1*w.x; aq[1].y += xv1*w.y; aq[1].z += xv1*w.z; aq[1].w += xv1*w.w;
            aq[2].x += xv2*w.x; aq[2].y += xv2*w.y; aq[2].z += xv2*w.z; aq[2].w += xv2*w.w;
            aq[3].x += xv3*w.x; aq[3].y += xv3*w.y; aq[3].z += xv3*w.z; aq[3].w += xv3*w.w;
            w = *(const float4*)&wk[i * 60];
            ak[0].x += xv0*w.x; ak[0].y += xv0*w.y; ak[0].z += xv0*w.z; ak[0].w += xv0*w.w;
            ak[1].x += xv1*w.x; ak[1].y += xv1*w.y; ak[1].z += xv1*w.z; ak[1].w += xv1*w.w;
            ak[2].x += xv2*w.x; ak[2].y += xv2*w.y; ak[2].z += xv2*w.z; ak[2].w += xv2*w.w;
            ak[3].x += xv3*w.x; ak[3].y += xv3*w.y; ak[3].z += xv3*w.z; ak[3].w += xv3*w.w;
            w = *(const float4*)&wv[i * 60];
            av[0].x += xv0*w.x; av[0].y += xv0*w.y; av[0].z += xv0*w.z; av[0].w += xv0*w.w;
            av[1].x += xv1*w.x; av[1].y += xv1*w.y; av[1].z += xv1*w.z; av[1].w += xv1*w.w;
            av[2].x += xv2*w.x; av[2].y += xv2*w.y; av[2].z += xv2*w.z; av[2].w += xv2*w.w;
            av[3].x += xv3*w.x; av[3].y += xv3*w.y; av[3].z += xv3*w.z; av[3].w += xv3*w.w;
        }
    }
    {
        const float* wq = Wqe + he * 6400 + jde;
        const float* wk = Wke + he * 6400 + jde;
        const float* xb = &xs[nl0 * 240 + he * 80];
        #pragma unroll 2
        for (int i = 0; i < 80; ++i) {
            float xv0 = xb[i], xv1 = xb[240 + i], xv2 = xb[480 + i], xv3 = xb[720 + i];
            float4 w;
            w = *(const float4*)&wq[i * 80];
            aqe[0].x += xv0*w.x; aqe[0].y += xv0*w.y; aqe[0].z += xv0*w.z; aqe[0].w += xv0*w.w;
            aqe[1].x += xv1*w.x; aqe[1].y += xv1*w.y; aqe[1].z += xv1*w.z; aqe[1].w += xv1*w.w;
            aqe[2].x += xv2*w.x; aqe[2].y += xv2*w.y; aqe[2].z += xv2*w.z; aqe[2].w += xv2*w.w;
            aqe[3].x += xv3*w.x; aqe[3].y += xv3*w.y; aqe[3].z += xv3*w.z; aqe[3].w += xv3*w.w;
            w = *(const float4*)&wk[i * 80];
            ake[0].x += xv0*w.x; ake[0].y += xv0*w.y; ake[0].z += xv0*w.z; ake[0].w += xv0*w.w;
            ake[1].x += xv1*w.x; ake[1].y += xv1*w.y; ake[1].z += xv1*w.z; ake[1].w += xv1*w.w;
            ake[2].x += xv2*w.x; ake[2].y += xv2*w.y; ake[2].z += xv2*w.z; ake[2].w += xv2*w.w;
            ake[3].x += xv3*w.x; ake[3].y += xv3*w.y; ake[3].z += xv3*w.z; ake[3].w += xv3*w.w;
        }
    }
    #pragma unroll
    for (int n = 0; n < 4; ++n) {
        const int node = base_node + nl0 + n;
        if (node >= N) break;
        const int ob = node * 240 + slot * 4;
        *(float4*)&q_inv[ob] = aq[n];
        *(float4*)&k_inv[ob] = ak[n];
        *(float4*)&v_inv[ob] = av[n];
        *(float4*)&q_ev[ob]  = aqe[n];
        *(float4*)&k_ev[ob]  = ake[n];
    }
}

// ---------------------------------------------------------------------------
// CSR build
// ---------------------------------------------------------------------------
__global__ __launch_bounds__(256) void hist_kernel(
    const int* __restrict__ rcv, int* __restrict__ counts, int E)
{
    int e = blockIdx.x * 256 + threadIdx.x;
    if (e < E) atomicAdd(&counts[rcv[e]], 1);
}

__global__ __launch_bounds__(1024) void scan_kernel(
    const int* __restrict__ counts, int* __restrict__ rowstart,
    int* __restrict__ cursor, int N)
{
    __shared__ int wsum[16];
    __shared__ int carry_s;
    if (threadIdx.x == 0) carry_s = 0;
    __syncthreads();
    const int lane = threadIdx.x & 63;
    const int w    = threadIdx.x >> 6;
    for (int base = 0; base < N; base += 1024) {
        const int i = base + threadIdx.x;
        int v = (i < N) ? counts[i] : 0;
        int x = v;
        #pragma unroll
        for (int off = 1; off < 64; off <<= 1) {
            int t = __shfl_up(x, off);
            if (lane >= off) x += t;
        }
        if (lane == 63) wsum[w] = x;
        __syncthreads();
        if (w == 0) {
            int s = (lane < 16) ? wsum[lane] : 0;
            #pragma unroll
            for (int off = 1; off < 16; off <<= 1) {
                int t = __shfl_up(s, off);
                if (lane >= off) s += t;
            }
            if (lane < 16) wsum[lane] = s;
        }
        __syncthreads();
        const int woff = (w == 0) ? 0 : wsum[w - 1];
        const int ex = carry_s + woff + x - v;
        if (i < N) { rowstart[i] = ex; cursor[i] = ex; }
        __syncthreads();
        if (threadIdx.x == 1023) carry_s += wsum[15];
    }
    __syncthreads();
    if (threadIdx.x == 0) rowstart[N] = carry_s;
}

__global__ __launch_bounds__(256) void scatter_kernel(
    const int* __restrict__ rcv, int* __restrict__ cursor,
    int* __restrict__ csr, int E)
{
    int e = blockIdx.x * 256 + threadIdx.x;
    if (e < E) {
        int pos = atomicAdd(&cursor[rcv[e]], 1);
        csr[pos] = e;
    }
}

// ---------------------------------------------------------------------------
// Per-edge SO3 invariants -> inv3[e][4]
// ---------------------------------------------------------------------------
__global__ __launch_bounds__(256) void inv3_kernel(
    const float* __restrict__ ev_f, const int* __restrict__ snd,
    const int* __restrict__ rcv, float* __restrict__ inv3, int E)
{
    int e = blockIdx.x * 256 + threadIdx.x;
    if (e >= E) return;
    const float* es = ev_f + (size_t)snd[e] * 15;
    const float* er = ev_f + (size_t)rcv[e] * 15;
    float i0 = 0.f, i1 = 0.f, i2 = 0.f;
    #pragma unroll
    for (int q = 0; q < 3; ++q)  { float d = es[q] - er[q]; i0 = fmaf(d, d, i0); }
    #pragma unroll
    for (int q = 3; q < 8; ++q)  { float d = es[q] - er[q]; i1 = fmaf(d, d, i1); }
    #pragma unroll
    for (int q = 8; q < 15; ++q) { float d = es[q] - er[q]; i2 = fmaf(d, d, i2); }
    *(float4*)(inv3 + (size_t)e * 4) = make_float4(i0, i1, i2, 0.f);
}

// ---------------------------------------------------------------------------
// Fused alpha kernel, CSR-ordered, EPT=1. blockIdx.y: 0=inv heads, 1=ev.
// 256 threads, 1 edge/thread -> 625 blocks/part (4.9 blocks/CU supplied).
// ONE 35x240 W staged in LDS (34.6 KB -> 4 blocks/CU cap); all W reads are
// wave-uniform broadcast ds_read_b128 (cheap). Low VGPR (~90) so occupancy
// is LDS-capped at 16 waves/CU, 2.5x R8 -> hides the L2/L3 k-row latency.
// alpha row at CSR position i: [aI0..3, aE0..2, snd_bits], cutoff folded.
// ---------------------------------------------------------------------------
__global__ __launch_bounds__(256, 3) void alpha_fused_kernel(
    const float* __restrict__ rbf, const float* __restrict__ inv3,
    const float* __restrict__ cut,
    const float* __restrict__ Wfi, const float* __restrict__ bfi,
    const float* __restrict__ Wfe, const float* __restrict__ bfe,
    const int* __restrict__ snd,   const int* __restrict__ rcv,
    const int* __restrict__ csr,
    const float* __restrict__ q_inv, const float* __restrict__ k_inv,
    const float* __restrict__ q_ev,  const float* __restrict__ k_ev,
    float* __restrict__ alpha, int E)
{
    __shared__ float WS[35 * 240];
    __shared__ float BS[240];
    const int part = blockIdx.y;              // 0 = inv, 1 = ev
    {
        const float* Wsrc = part ? Wfe : Wfi;
        const float* bsrc = part ? bfe : bfi;
        for (int idx = threadIdx.x; idx < 35 * 240; idx += 256)
            WS[idx] = Wsrc[idx];
        for (int idx = threadIdx.x; idx < 240; idx += 256)
            BS[idx] = bsrc[idx];
    }
    __syncthreads();

    int i = blockIdx.x * 256 + threadIdx.x;
    if (i >= E) i = E - 1;                    // clamp: benign duplicate work
    const int e = csr[i];
    const int s = snd[e], r = rcv[e];
    const float c = cut[e];

    float f[35];
    {
        const float4* rb = (const float4*)(rbf + (size_t)e * 32);
        #pragma unroll
        for (int k4 = 0; k4 < 8; ++k4) {
            float4 a = rb[k4];
            f[k4*4+0] = a.x; f[k4*4+1] = a.y; f[k4*4+2] = a.z; f[k4*4+3] = a.w;
        }
        float4 v3 = *(const float4*)(inv3 + (size_t)e * 4);
        f[32] = v3.x; f[33] = v3.y; f[34] = v3.z;
    }

    if (part == 0) {
        const float s60 = 0.12909944487358056f;   // 1/sqrt(60)
        const float* qb = q_inv + (size_t)r * 240;
        const float* kb = k_inv + (size_t)s * 240;
        float out[4];
        #pragma unroll
        for (int h = 0; h < 4; ++h) {
            float acc = 0.f;
            #pragma unroll 1
            for (int j4 = 0; j4 < 15; ++j4) {
                const int j = h * 60 + j4 * 4;
                float4 fw = *(const float4*)&BS[j];
                #pragma unroll
                for (int k = 0; k < 35; ++k) {
                    const float4 w = *(const float4*)&WS[k * 240 + j];
                    const float fk = f[k];
                    fw.x = fmaf(fk, w.x, fw.x); fw.y = fmaf(fk, w.y, fw.y);
                    fw.z = fmaf(fk, w.z, fw.z); fw.w = fmaf(fk, w.w, fw.w);
                }
                const float4 q  = *(const float4*)(qb + j);
                const float4 kk = *(const float4*)(kb + j);
                acc += q.x*kk.x*fw.x + q.y*kk.y*fw.y
                     + q.z*kk.z*fw.z + q.w*kk.w*fw.w;
            }
            out[h] = acc * s60 * c;
        }
        *(float4*)(alpha + (size_t)i * 8) = make_float4(out[0], out[1], out[2], out[3]);
        alpha[(size_t)i * 8 + 7] = __int_as_float(s);
    } else {
        const float s80 = 0.11180339887498948f;   // 1/sqrt(80)
        const float* qb = q_ev + (size_t)r * 240;
        const float* kb = k_ev + (size_t)s * 240;
        #pragma unroll
        for (int h = 0; h < 3; ++h) {
            float acc = 0.f;
            #pragma unroll 1
            for (int j4 = 0; j4 < 20; ++j4) {
                const int j = h * 80 + j4 * 4;
                float4 fw = *(const float4*)&BS[j];
                #pragma unroll
                for (int k = 0; k < 35; ++k) {
                    const float4 w = *(const float4*)&WS[k * 240 + j];
                    const float fk = f[k];
                    fw.x = fmaf(fk, w.x, fw.x); fw.y = fmaf(fk, w.y, fw.y);
                    fw.z = fmaf(fk, w.z, fw.z); fw.w = fmaf(fk, w.w, fw.w);
                }
                const float4 q  = *(const float4*)(qb + j);
                const float4 kk = *(const float4*)(kb + j);
                acc += q.x*kk.x*fw.x + q.y*kk.y*fw.y
                     + q.z*kk.z*fw.z + q.w*kk.w*fw.w;
            }
            alpha[(size_t)i * 8 + 4 + h] = acc * s80 * c;
        }
    }
}

// ---------------------------------------------------------------------------
// Gather: one block per receiver; alpha indexed by CSR position.
// ---------------------------------------------------------------------------
__global__ __launch_bounds__(256) void gather_kernel(
    const int* __restrict__ rowstart, const int* __restrict__ csr,
    const float* __restrict__ alpha,
    const float* __restrict__ v_inv, const float* __restrict__ sh,
    float* __restrict__ dinv, float* __restrict__ dev)
{
    const int r = blockIdx.x;
    const int c = threadIdx.x;
    const int beg = rowstart[r], end = rowstart[r + 1];

    __shared__ float sal[64][8];
    __shared__ int   sed[64];

    float acc = 0.f;
    for (int chunk = beg; chunk < end; chunk += 64) {
        const int len = min(64, end - chunk);
        __syncthreads();
        if (c < len) {
            const float4* ap = (const float4*)(alpha + (size_t)(chunk + c) * 8);
            const float4 a0 = ap[0], a1 = ap[1];
            *(float4*)&sal[c][0] = a0;
            *(float4*)&sal[c][4] = a1;
            sed[c] = csr[chunk + c];
        }
        __syncthreads();
        if (c < 240) {
            const int h = c / 60;
            #pragma unroll 4
            for (int i = 0; i < len; ++i) {
                const int s = __float_as_int(sal[i][7]);
                acc += sal[i][h] * v_inv[(size_t)s * 240 + c];
            }
        } else if (c < 255) {
            const int i0 = c - 240;
            const int h = (i0 < 3) ? 4 : ((i0 < 8) ? 5 : 6);
            for (int i = 0; i < len; ++i)
                acc += sal[i][h] * sh[(size_t)sed[i] * 15 + i0];
        }
    }
    if (c < 240) dinv[(size_t)r * 240 + c] = acc;
    else if (c < 255) dev[(size_t)r * 15 + (c - 240)] = acc;
}

extern "C" void kernel_launch(void* const* d_in, const int* in_sizes, int n_in,
                              void* d_out, int out_size, void* d_ws, size_t ws_size,
                              hipStream_t stream) {
    const float* inv_f = (const float*)d_in[0];
    const float* ev_f  = (const float*)d_in[1];
    const float* rbf   = (const float*)d_in[2];
    const float* sh    = (const float*)d_in[3];
    const float* cut   = (const float*)d_in[4];
    const float* Wq    = (const float*)d_in[5];
    const float* Wk    = (const float*)d_in[6];
    const float* Wv    = (const float*)d_in[7];
    const float* Wqe   = (const float*)d_in[8];
    const float* Wke   = (const float*)d_in[9];
    const float* Wfi   = (const float*)d_in[10];
    const float* bfi   = (const float*)d_in[11];
    const float* Wfe   = (const float*)d_in[12];
    const float* bfe   = (const float*)d_in[13];
    const int*   snd   = (const int*)d_in[14];
    const int*   rcv   = (const int*)d_in[15];

    const int N = in_sizes[0] / 240;
    const int E = in_sizes[14];

    float* out  = (float*)d_out;
    float* dinv = out;                       // [N,240]
    float* dev  = out + (size_t)N * 240;     // [N,15]

    float* ws = (float*)d_ws;
    const size_t Nf = (size_t)N * 240;
    float* q_inv = ws + 0 * Nf;
    float* k_inv = ws + 1 * Nf;
    float* v_inv = ws + 2 * Nf;
    float* q_ev  = ws + 3 * Nf;
    float* k_ev  = ws + 4 * Nf;
    float* alpha = ws + 5 * Nf;                           // E*8 floats
    float* inv3  = alpha + (size_t)E * 8;                 // E*4 floats
    int*   ibase    = (int*)(inv3 + (size_t)E * 4);
    int*   counts   = ibase;                              // N
    int*   rowstart = ibase + N;                          // N+1
    int*   cursor   = ibase + 2 * N + 1;                  // N
    int*   csr      = ibase + 3 * N + 1;                  // E

    hipMemsetAsync(counts, 0, (size_t)N * sizeof(int), stream);

    const int eb = (E + 255) / 256;
    hist_kernel<<<eb, 256, 0, stream>>>(rcv, counts, E);
    scan_kernel<<<1, 1024, 0, stream>>>(counts, rowstart, cursor, N);
    scatter_kernel<<<eb, 256, 0, stream>>>(rcv, cursor, csr, E);

    proj_kernel<<<(N + PNPB - 1) / PNPB, 512, 0, stream>>>(
        inv_f, Wq, Wk, Wv, Wqe, Wke, q_inv, k_inv, v_inv, q_ev, k_ev, N);

    inv3_kernel<<<eb, 256, 0, stream>>>(ev_f, snd, rcv, inv3, E);

    alpha_fused_kernel<<<dim3(eb, 2), 256, 0, stream>>>(
        rbf, inv3, cut, Wfi, bfi, Wfe, bfe, snd, rcv, csr,
        q_inv, k_inv, q_ev, k_ev, alpha, E);

    gather_kernel<<<N, 256, 0, stream>>>(
        rowstart, csr, alpha, v_inv, sh, dinv, dev);
}